// Round 4
// baseline (366.687 us; speedup 1.0000x reference)
//
#include <hip/hip_runtime.h>

// Fused 2-layer LSTM (H=64) + Dense(64,sigmoid) + Dense(1,sigmoid), MFMA bf16.
// Transposed-z formulation: z^T[gate-unit, batch] = Wt @ [x|h]^T.
// B=4096, T=256, F=32. One WG = 1024 threads = 16 waves handles BB=16 rows.
//
// SPLIT-PHASE ANTI-PHASED SCHEDULE (2 barriers/step): each LSTM step is split
// into M (LDS reads + MFMA -> z kept in VGPRs) and G (gate trans math + h
// write). L1 and L2 wave groups run anti-phased so every barrier interval
// mixes MFMA/LDS-phase waves with trans-phase waves on each SIMD:
//   even interval: L1.M(u)      || L2.G(u-2)   (z2 from regs -> h2[u-2])
//   odd  interval: L1.G(u)      || L2.M(u-1)   (reads h1[u-1], h2[u-2])
// Dependencies: L2 lags L1 by 2 steps; all LDS reads are >=1 barrier from
// their writes (parity double-buffers; verified per-interval). In-loop
// barrier is raw "s_waitcnt lgkmcnt(0); s_barrier" -- NO vmcnt(0) drain, so
// the x HBM prefetch stays in flight across barriers.
//
// h layout: [batch][unit] stride 64 shorts (128 B), XOR-swizzled per 16B
// chunk: chunk' = chunk ^ (batch&7)  -> conflict-free ds_read_b128.
// Tile->unit map: unit = wv*8 + ugl*2 + tt, so lane (n,q) owns 2 CONSECUTIVE
// units {wv*8+q*2+tt} -> one b32 packed (v_cvt_pk_bf16_f32) h-write per step.
// Activation scales folded into weights (i,f,o: -log2e; g: +2*log2e); cell
// state kept pre-scaled by 2*log2e. Bias enters as the MFMA C operand.
// MFMA 16x16x32 layouts (learn_hip-verified):
//   A[m=lane&15][k=(lane>>4)*8+j], B[k=(lane>>4)*8+j][n=lane&15],
//   C/D: col=lane&15, row=(lane>>4)*4+reg.

typedef __attribute__((ext_vector_type(8))) short short8;
typedef __attribute__((ext_vector_type(4))) float floatx4;
typedef __attribute__((ext_vector_type(2))) float floatx2;

__device__ __forceinline__ float ex2(float x){ return __builtin_amdgcn_exp2f(x); }
__device__ __forceinline__ float rcp_(float x){ return __builtin_amdgcn_rcpf(x); }
__device__ __forceinline__ float sigm(float x){ return rcp_(1.0f + ex2(-1.44269504f*x)); }
__device__ __forceinline__ unsigned bfbits(float f){       // RNE f32->bf16 (raw bits)
    unsigned u = __builtin_bit_cast(unsigned, f);
    u += 0x7FFFu + ((u >> 16) & 1u);
    return u >> 16;
}
__device__ __forceinline__ short f2bf(float f){ return (short)bfbits(f); }
// HW packed RNE f32->2xbf16 (bit-identical to bfbits for normals; inputs are
// sigmoid/tanh products, always normal).
__device__ __forceinline__ unsigned cvtpk(float lo, float hi){
    unsigned r;
    asm("v_cvt_pk_bf16_f32 %0, %1, %2" : "=v"(r) : "v"(lo), "v"(hi));
    return r;
}
// Workgroup barrier WITHOUT vmcnt drain: LDS ordering via lgkmcnt(0) only.
__device__ __forceinline__ void wg_barrier_lds(){
    asm volatile("s_waitcnt lgkmcnt(0)\n\ts_barrier" ::: "memory");
}
// Gate math for one cell: z = (zi,zf,zg,zo) pre-scaled; c pre-scaled by 2LG.
__device__ __forceinline__ float gate_update(const floatx4& z, float& c){
    float iv = rcp_(1.0f + ex2(z[0]));
    float fv = rcp_(1.0f + ex2(z[1]));
    float rg = rcp_(1.0f + ex2(z[2]));
    float ov = rcp_(1.0f + ex2(z[3]));
    float gp = fmaf(-5.77078016f, rg, 2.88539008f);          // 2LG*tanh(zg)
    c = fmaf(fv, c, iv * gp);
    float th = fmaf(-2.0f, rcp_(1.0f + ex2(c)), 1.0f);       // tanh(c/2LG)
    return ov * th;
}

#define MFMA_BF16 __builtin_amdgcn_mfma_f32_16x16x32_bf16

__global__ __launch_bounds__(1024, 1)
void lstm2_tz(const float* __restrict__ x,
              const float* __restrict__ W1, const float* __restrict__ U1, const float* __restrict__ b1,
              const float* __restrict__ W2, const float* __restrict__ U2, const float* __restrict__ b2,
              const float* __restrict__ Wd, const float* __restrict__ bd,
              const float* __restrict__ Wo, const float* __restrict__ bo,
              float* __restrict__ out)
{
    __shared__ __align__(16) short h1b[2][16 * 64];   // [buf][batch*64 + swz-unit]
    __shared__ __align__(16) short h2b[2][16 * 64];
    __shared__ __align__(16) short xsb[2][16 * 40];   // [buf][batch*40 + feat]
    __shared__ float psum[4][16];

    const int tid  = threadIdx.x;
    const int w    = tid >> 6;            // 0..15
    const bool isL1 = (w < 8);
    const int wv   = w & 7;               // 0..7 within group
    const int lane = tid & 63;
    const int n    = lane & 15;           // B-frag col = batch row; also A-frag m
    const int q    = lane >> 4;           // quad
    const int b0   = blockIdx.x * 16;

    const float LG = 1.44269504f;         // log2(e)

    // A-frag row mapping: within-tile row m -> (unit_local = m>>2, gate = m&3)
    const int ugl = n >> 2;
    const int gA  = n & 3;
    const float sA = (gA == 2) ? (2.0f * LG) : (-LG);

    // ---- per-lane LDS offsets (shorts), swizzle sw = n&7 on 16B chunks ----
    const int sw   = n & 7;
    const int hro0 = n * 64 + ((q ^ sw) << 3);          // h chunk q      (k 0..31)
    const int hro1 = n * 64 + (((4 + q) ^ sw) << 3);    // h chunk 4+q    (k 32..63)
    const int xro  = n * 40 + q * 8;
    // write: units wv*8+q*2+{0,1} -> chunk wv, in-chunk q*2 shorts (b32 store)
    const int hwo  = n * 64 + ((wv ^ sw) << 3) + q * 2;

    // ---- one-time: weight A-fragments + bias C vectors ----
    short8  Wa[8];
    floatx4 bC[2];
    if (isL1) {
#pragma unroll
        for (int tt = 0; tt < 2; ++tt) {
            const int un   = wv * 8 + ugl * 2 + tt;     // A-frag output unit
            const int ncol = gA * 64 + un;
#pragma unroll
            for (int j = 0; j < 8; ++j) {
                const int k = q * 8 + j;
                Wa[tt * 3 + 0][j] = f2bf(W1[k * 256 + ncol] * sA);
                Wa[tt * 3 + 1][j] = f2bf(U1[k * 256 + ncol] * sA);
                Wa[tt * 3 + 2][j] = f2bf(U1[(32 + k) * 256 + ncol] * sA);
            }
#pragma unroll
            for (int r = 0; r < 4; ++r)
                bC[tt][r] = b1[r * 64 + wv * 8 + q * 2 + tt] * ((r == 2) ? (2.0f * LG) : (-LG));
        }
    } else {
#pragma unroll
        for (int tt = 0; tt < 2; ++tt) {
            const int un   = wv * 8 + ugl * 2 + tt;
            const int ncol = gA * 64 + un;
#pragma unroll
            for (int j = 0; j < 8; ++j) {
                const int k = q * 8 + j;
                Wa[tt * 4 + 0][j] = f2bf(W2[k * 256 + ncol] * sA);
                Wa[tt * 4 + 1][j] = f2bf(W2[(32 + k) * 256 + ncol] * sA);
                Wa[tt * 4 + 2][j] = f2bf(U2[k * 256 + ncol] * sA);
                Wa[tt * 4 + 3][j] = f2bf(U2[(32 + k) * 256 + ncol] * sA);
            }
#pragma unroll
            for (int r = 0; r < 4; ++r)
                bC[tt][r] = b2[r * 64 + wv * 8 + q * 2 + tt] * ((r == 2) ? (2.0f * LG) : (-LG));
        }
    }

    // ---- zero h double-buffers (2 arrays x 2048 shorts = 1024 dwords each) ----
    {
        unsigned* p1 = (unsigned*)&h1b[0][0];
        unsigned* p2 = (unsigned*)&h2b[0][0];
        for (int i = tid; i < 1024; i += 1024) { p1[i] = 0u; p2[i] = 0u; }
    }

    // ---- x staging (tid<256 = L1 waves 0-3): 2 fp32 of row (tid>>4)/step ----
    const int xr = tid >> 4;
    const int xc = (tid & 15) * 2;
    const float* xrow = x + (size_t)(b0 + xr) * 8192 + xc;   // T*F = 8192
    floatx2 xv0;
    if (tid < 256) {
        floatx2 v = *(const floatx2*)xrow;                    // x[0]
        *(unsigned*)&xsb[0][xr * 40 + xc] = cvtpk(v.x, v.y);
        xv0 = *(const floatx2*)(xrow + 32);                   // x[1]
    }
    __syncthreads();

    float c[2] = {0, 0};                  // cell state, pre-scaled by 2*log2e
    floatx4 z[2];                         // pre-activation, carried M -> G

    for (int u = 0; u <= 257; ++u) {
        const int par = u & 1, pax = par ^ 1;

        // ===== even interval: L1.M(u)  ||  L2.G(u-2) =====
        if (isL1) {
            if (u < 256) {
                const short* hR = &h1b[pax][0];              // h1[u-1]
                short8 bx  = *(const short8*)&xsb[par][xro]; // x[u]
                short8 bh0 = *(const short8*)&hR[hro0];
                short8 bh1 = *(const short8*)&hR[hro1];
                // stage x[u+1] into other buffer; prefetch x[u+2] (in flight
                // across barriers -- no vmcnt drain in loop).
                if (tid < 256 && u < 255) {
                    *(unsigned*)&xsb[pax][xr * 40 + xc] = cvtpk(xv0.x, xv0.y);
                    if (u < 254) xv0 = *(const floatx2*)(xrow + (size_t)(u + 2) * 32);
                }
#pragma unroll
                for (int tt = 0; tt < 2; ++tt) {
                    floatx4 zz = bC[tt];
                    zz = MFMA_BF16(Wa[tt * 3 + 0], bx,  zz, 0, 0, 0);
                    zz = MFMA_BF16(Wa[tt * 3 + 1], bh0, zz, 0, 0, 0);
                    zz = MFMA_BF16(Wa[tt * 3 + 2], bh1, zz, 0, 0, 0);
                    z[tt] = zz;
                }
            }
        } else {
            if (u >= 2) {                                    // L2.G(u-2)
                float hv0 = gate_update(z[0], c[0]);
                float hv1 = gate_update(z[1], c[1]);
                *(unsigned*)&h2b[par][hwo] = cvtpk(hv0, hv1); // h2[u-2], parity par
            }
        }
        wg_barrier_lds();

        // ===== odd interval: L1.G(u)  ||  L2.M(u-1) =====
        if (isL1) {
            if (u < 256) {                                   // L1.G(u)
                float hv0 = gate_update(z[0], c[0]);
                float hv1 = gate_update(z[1], c[1]);
                *(unsigned*)&h1b[par][hwo] = cvtpk(hv0, hv1); // h1[u], parity par
            }
        } else {
            if (u >= 1 && u <= 256) {                        // L2.M(u-1)
                const short* hR = &h1b[pax][0];              // h1[u-1], parity pax
                const short* gR = &h2b[par][0];              // h2[u-2], parity par
                short8 bh0 = *(const short8*)&hR[hro0];
                short8 bh1 = *(const short8*)&hR[hro1];
                short8 bg0 = *(const short8*)&gR[hro0];
                short8 bg1 = *(const short8*)&gR[hro1];
#pragma unroll
                for (int tt = 0; tt < 2; ++tt) {
                    floatx4 zz = bC[tt];
                    zz = MFMA_BF16(Wa[tt * 4 + 0], bh0, zz, 0, 0, 0);
                    zz = MFMA_BF16(Wa[tt * 4 + 1], bh1, zz, 0, 0, 0);
                    zz = MFMA_BF16(Wa[tt * 4 + 2], bg0, zz, 0, 0, 0);
                    zz = MFMA_BF16(Wa[tt * 4 + 3], bg1, zz, 0, 0, 0);
                    z[tt] = zz;
                }
            }
        }
        wg_barrier_lds();
    }

    // ---- epilogue (waves 8-11): h_last = h2[255] in h2b[1] ----
    // Dense(64,sigmoid): A = h2 rows (swizzled read), B = Wd columns.
    if (!isL1 && wv < 4) {
        const int colD = wv * 16 + n;
        short8 wd0, wd1;
#pragma unroll
        for (int j = 0; j < 8; ++j) {
            wd0[j] = f2bf(Wd[(q * 8 + j) * 64 + colD] * (-LG));
            wd1[j] = f2bf(Wd[(32 + q * 8 + j) * 64 + colD] * (-LG));
        }
        short8 hA0 = *(const short8*)&h2b[1][hro0];
        short8 hA1 = *(const short8*)&h2b[1][hro1];
        const float bdv = bd[colD] * (-LG);
        floatx4 dacc = { bdv, bdv, bdv, bdv };
        dacc = MFMA_BF16(hA0, wd0, dacc, 0, 0, 0);
        dacc = MFMA_BF16(hA1, wd1, dacc, 0, 0, 0);
        const float wo = Wo[colD];
#pragma unroll
        for (int r = 0; r < 4; ++r) {
            float p = rcp_(1.0f + ex2(dacc[r])) * wo;   // sigm (scale folded)
            p += __shfl_xor(p, 1, 64);
            p += __shfl_xor(p, 2, 64);
            p += __shfl_xor(p, 4, 64);
            p += __shfl_xor(p, 8, 64);                  // sum over 16 dense units
            if (n == 0) psum[wv][q * 4 + r] = p;
        }
    }
    __syncthreads();
    if (tid < 16) {
        float s = psum[0][tid] + psum[1][tid] + psum[2][tid] + psum[3][tid] + bo[0];
        out[b0 + tid] = sigm(s);
    }
}

extern "C" void kernel_launch(void* const* d_in, const int* in_sizes, int n_in,
                              void* d_out, int out_size, void* d_ws, size_t ws_size,
                              hipStream_t stream) {
    (void)in_sizes; (void)n_in; (void)d_ws; (void)ws_size; (void)out_size;
    const float* x  = (const float*)d_in[0];
    const float* W1 = (const float*)d_in[1];
    const float* U1 = (const float*)d_in[2];
    const float* b1 = (const float*)d_in[3];
    const float* W2 = (const float*)d_in[4];
    const float* U2 = (const float*)d_in[5];
    const float* b2 = (const float*)d_in[6];
    const float* Wd = (const float*)d_in[7];
    const float* bd = (const float*)d_in[8];
    const float* Wo = (const float*)d_in[9];
    const float* bo = (const float*)d_in[10];
    lstm2_tz<<<dim3(256), dim3(1024), 0, stream>>>(
        x, W1, U1, b1, W2, U2, b2, Wd, bd, Wo, bo, (float*)d_out);
}

// Round 5
// 330.458 us; speedup vs baseline: 1.1096x; 1.1096x over previous
//
#include <hip/hip_runtime.h>

// Fused 2-layer LSTM (H=64) + Dense(64,sigmoid) + Dense(1,sigmoid), MFMA bf16.
// Transposed-z formulation: z^T[gate-unit, batch] = Wt @ [x|h]^T.
// B=4096, T=256, F=32. One WG = 1024 threads = 16 waves handles BB=16 rows.
// Waves 0-7 (L1): layer 1 step u, 2 M-tiles each; waves 8-15 (L2): layer 2
// step u-1, 2 M-tiles each. One barrier per step; double-buffered h1/h2/x.
//
// ISSUE-BOUND consolidation (R5): counters show the SIMD issue port is the
// binding resource (VALUBusy 60% incl MFMA 23%, invariant under conflicts/
// occupancy/barrier changes). This round cuts issued instructions:
//  - u-loop explicitly unrolled x2 with STATIC parity: h-buffer bases are
//    compile-time, no per-step v_cndmask/selects, half the loop SALU.
//  - batched reciprocal in gate math: the 4 gate sigmoids share ONE v_rcp
//    via product inversion (4 rcp -> 1 rcp + 9 mul, -6 issue cyc/cell;
//    rcp rel err ~2^-22 -- invisible at bf16 output).
// In-loop barrier stays raw "s_waitcnt lgkmcnt(0); s_barrier" (no vmcnt
// drain; x HBM prefetch stays in flight). h layout: stride 64 shorts,
// XOR-swizzled per 16B chunk (chunk' = chunk ^ (batch&7)) -> conflict-free
// ds_read_b128. Lane (n,q) owns 2 consecutive units -> one b32
// v_cvt_pk_bf16_f32 h-write per step. Activation scales folded into weights
// (i,f,o: -log2e; g: +2*log2e); cell state pre-scaled by 2*log2e; bias via
// MFMA C operand.
// MFMA 16x16x32 layouts (learn_hip-verified):
//   A[m=lane&15][k=(lane>>4)*8+j], B[k=(lane>>4)*8+j][n=lane&15],
//   C/D: col=lane&15, row=(lane>>4)*4+reg.

typedef __attribute__((ext_vector_type(8))) short short8;
typedef __attribute__((ext_vector_type(4))) float floatx4;
typedef __attribute__((ext_vector_type(2))) float floatx2;

__device__ __forceinline__ float ex2(float x){ return __builtin_amdgcn_exp2f(x); }
__device__ __forceinline__ float rcp_(float x){ return __builtin_amdgcn_rcpf(x); }
__device__ __forceinline__ float sigm(float x){ return rcp_(1.0f + ex2(-1.44269504f*x)); }
__device__ __forceinline__ unsigned bfbits(float f){       // RNE f32->bf16 (raw bits)
    unsigned u = __builtin_bit_cast(unsigned, f);
    u += 0x7FFFu + ((u >> 16) & 1u);
    return u >> 16;
}
__device__ __forceinline__ short f2bf(float f){ return (short)bfbits(f); }
// HW packed RNE f32->2xbf16 (bit-identical to bfbits for normals).
__device__ __forceinline__ unsigned cvtpk(float lo, float hi){
    unsigned r;
    asm("v_cvt_pk_bf16_f32 %0, %1, %2" : "=v"(r) : "v"(lo), "v"(hi));
    return r;
}
// Workgroup barrier WITHOUT vmcnt drain: LDS ordering via lgkmcnt(0) only.
__device__ __forceinline__ void wg_barrier_lds(){
    asm volatile("s_waitcnt lgkmcnt(0)\n\ts_barrier" ::: "memory");
}
// Gate math, batched-rcp: 5 ex2 + 2 rcp (was 5 rcp). z pre-scaled
// (i,f,o: -LG; g: +2LG); c pre-scaled by 2*log2e.
__device__ __forceinline__ float gate_update(const floatx4& z, float& c){
    float ea = 1.0f + ex2(z[0]);                 // 1+e for i
    float eb = 1.0f + ex2(z[1]);                 // 1+e for f
    float eg = 1.0f + ex2(z[2]);                 // 1+e for g-sigmoid
    float eo = 1.0f + ex2(z[3]);                 // 1+e for o
    float ab = ea * eb, gd = eg * eo;
    float r  = rcp_(ab * gd);                    // 1/(ea eb eg eo)
    float gdr = gd * r, abr = ab * r;            // 1/(ea eb), 1/(eg eo)
    float iv = eb * gdr;                         // 1/ea
    float fv = ea * gdr;                         // 1/eb
    float rg = eo * abr;                         // 1/eg
    float ov = eg * abr;                         // 1/eo
    float gp = fmaf(-5.77078016f, rg, 2.88539008f);   // 2LG*tanh(zg)
    c = fmaf(fv, c, iv * gp);
    float th = fmaf(-2.0f, rcp_(1.0f + ex2(c)), 1.0f); // tanh(c/2LG)
    return ov * th;
}

#define MFMA_BF16 __builtin_amdgcn_mfma_f32_16x16x32_bf16

__global__ __launch_bounds__(1024, 1)
void lstm2_tz(const float* __restrict__ x,
              const float* __restrict__ W1, const float* __restrict__ U1, const float* __restrict__ b1,
              const float* __restrict__ W2, const float* __restrict__ U2, const float* __restrict__ b2,
              const float* __restrict__ Wd, const float* __restrict__ bd,
              const float* __restrict__ Wo, const float* __restrict__ bo,
              float* __restrict__ out)
{
    __shared__ __align__(16) short h1b[2][16 * 64];   // [buf][batch*64 + swz-unit]
    __shared__ __align__(16) short h2b[2][16 * 64];
    __shared__ __align__(16) short xsb[2][16 * 40];   // [buf][batch*40 + feat]
    __shared__ float psum[4][16];

    const int tid  = threadIdx.x;
    const int w    = tid >> 6;            // 0..15
    const bool isL1 = (w < 8);
    const int wv   = w & 7;               // 0..7 within group
    const int lane = tid & 63;
    const int n    = lane & 15;           // B-frag col = batch row; also A-frag m
    const int q    = lane >> 4;           // quad
    const int b0   = blockIdx.x * 16;

    const float LG = 1.44269504f;         // log2(e)

    // A-frag row mapping: within-tile row m -> (unit_local = m>>2, gate = m&3)
    const int ugl = n >> 2;
    const int gA  = n & 3;
    const float sA = (gA == 2) ? (2.0f * LG) : (-LG);

    // ---- per-lane LDS offsets (shorts), swizzle sw = n&7 on 16B chunks ----
    const int sw   = n & 7;
    const int hro0 = n * 64 + ((q ^ sw) << 3);          // h chunk q      (k 0..31)
    const int hro1 = n * 64 + (((4 + q) ^ sw) << 3);    // h chunk 4+q    (k 32..63)
    const int xro  = n * 40 + q * 8;
    // write: units wv*8+q*2+{0,1} -> chunk wv, in-chunk q*2 shorts (b32 store)
    const int hwo  = n * 64 + ((wv ^ sw) << 3) + q * 2;

    // ---- one-time: weight A-fragments + bias C vectors ----
    short8  Wa[8];
    floatx4 bC[2];
    if (isL1) {
#pragma unroll
        for (int tt = 0; tt < 2; ++tt) {
            const int un   = wv * 8 + ugl * 2 + tt;     // A-frag output unit
            const int ncol = gA * 64 + un;
#pragma unroll
            for (int j = 0; j < 8; ++j) {
                const int k = q * 8 + j;
                Wa[tt * 3 + 0][j] = f2bf(W1[k * 256 + ncol] * sA);
                Wa[tt * 3 + 1][j] = f2bf(U1[k * 256 + ncol] * sA);
                Wa[tt * 3 + 2][j] = f2bf(U1[(32 + k) * 256 + ncol] * sA);
            }
#pragma unroll
            for (int r = 0; r < 4; ++r)
                bC[tt][r] = b1[r * 64 + wv * 8 + q * 2 + tt] * ((r == 2) ? (2.0f * LG) : (-LG));
        }
    } else {
#pragma unroll
        for (int tt = 0; tt < 2; ++tt) {
            const int un   = wv * 8 + ugl * 2 + tt;
            const int ncol = gA * 64 + un;
#pragma unroll
            for (int j = 0; j < 8; ++j) {
                const int k = q * 8 + j;
                Wa[tt * 4 + 0][j] = f2bf(W2[k * 256 + ncol] * sA);
                Wa[tt * 4 + 1][j] = f2bf(W2[(32 + k) * 256 + ncol] * sA);
                Wa[tt * 4 + 2][j] = f2bf(U2[k * 256 + ncol] * sA);
                Wa[tt * 4 + 3][j] = f2bf(U2[(32 + k) * 256 + ncol] * sA);
            }
#pragma unroll
            for (int r = 0; r < 4; ++r)
                bC[tt][r] = b2[r * 64 + wv * 8 + q * 2 + tt] * ((r == 2) ? (2.0f * LG) : (-LG));
        }
    }

    // ---- zero h double-buffers ----
    {
        unsigned* p1 = (unsigned*)&h1b[0][0];
        unsigned* p2 = (unsigned*)&h2b[0][0];
        for (int i = tid; i < 1024; i += 1024) { p1[i] = 0u; p2[i] = 0u; }
    }

    // ---- x staging (tid<256 = L1 waves 0-3): 2 fp32 of row (tid>>4)/step ----
    const int xr = tid >> 4;
    const int xc = (tid & 15) * 2;
    const float* xrow = x + (size_t)(b0 + xr) * 8192 + xc;   // T*F = 8192
    floatx2 xv0;
    if (tid < 256) {
        floatx2 v = *(const floatx2*)xrow;                    // x[0]
        *(unsigned*)&xsb[0][xr * 40 + xc] = cvtpk(v.x, v.y);
        xv0 = *(const floatx2*)(xrow + 32);                   // x[1]
    }
    __syncthreads();

    float c[2] = {0, 0};                  // cell state, pre-scaled by 2*log2e

    // One LSTM step at compile-time parity PAR (reads h[1-PAR], writes h[PAR]).
#define LSTM_STEP(U, PAR)                                                     \
    {                                                                         \
        const int u_ = (U);                                                   \
        if (isL1) {                                                           \
            if (u_ < 256) {                                                   \
                const short* hR = &h1b[1 - (PAR)][0];                         \
                short8 bx  = *(const short8*)&xsb[(PAR)][xro];                \
                short8 bh0 = *(const short8*)&hR[hro0];                       \
                short8 bh1 = *(const short8*)&hR[hro1];                       \
                if (tid < 256 && u_ < 255) {                                  \
                    *(unsigned*)&xsb[1 - (PAR)][xr * 40 + xc] = cvtpk(xv0.x, xv0.y); \
                    if (u_ < 254) xv0 = *(const floatx2*)(xrow + (size_t)(u_ + 2) * 32); \
                }                                                             \
                float hv[2];                                                  \
                _Pragma("unroll")                                             \
                for (int tt = 0; tt < 2; ++tt) {                              \
                    floatx4 z = bC[tt];                                       \
                    z = MFMA_BF16(Wa[tt * 3 + 0], bx,  z, 0, 0, 0);           \
                    z = MFMA_BF16(Wa[tt * 3 + 1], bh0, z, 0, 0, 0);           \
                    z = MFMA_BF16(Wa[tt * 3 + 2], bh1, z, 0, 0, 0);           \
                    hv[tt] = gate_update(z, c[tt]);                           \
                }                                                             \
                *(unsigned*)&h1b[(PAR)][hwo] = cvtpk(hv[0], hv[1]);           \
            }                                                                 \
        } else {                                                              \
            if (u_ >= 1 && u_ <= 256) {                                       \
                const short* hR = &h1b[1 - (PAR)][0];                         \
                const short* gR = &h2b[(PAR)][0];                             \
                short8 bh0 = *(const short8*)&hR[hro0];                       \
                short8 bh1 = *(const short8*)&hR[hro1];                       \
                short8 bg0 = *(const short8*)&gR[hro0];                       \
                short8 bg1 = *(const short8*)&gR[hro1];                       \
                float hv[2];                                                  \
                _Pragma("unroll")                                             \
                for (int tt = 0; tt < 2; ++tt) {                              \
                    floatx4 z = bC[tt];                                       \
                    z = MFMA_BF16(Wa[tt * 4 + 0], bh0, z, 0, 0, 0);           \
                    z = MFMA_BF16(Wa[tt * 4 + 1], bh1, z, 0, 0, 0);           \
                    z = MFMA_BF16(Wa[tt * 4 + 2], bg0, z, 0, 0, 0);           \
                    z = MFMA_BF16(Wa[tt * 4 + 3], bg1, z, 0, 0, 0);           \
                    hv[tt] = gate_update(z, c[tt]);                           \
                }                                                             \
                *(unsigned*)&h2b[1 - (PAR)][hwo] = cvtpk(hv[0], hv[1]);       \
            }                                                                 \
        }                                                                     \
        wg_barrier_lds();                                                     \
    }

    // u = 0..257 (u=257 is a barrier-only pad step), static parity via x2 unroll.
    for (int uu = 0; uu < 258; uu += 2) {
        LSTM_STEP(uu,     0)
        LSTM_STEP(uu + 1, 1)
    }
#undef LSTM_STEP

    // ---- epilogue (waves 8-11): h_last = h2[255] in h2b[1] ----
    // Dense(64,sigmoid): A = h2 rows (swizzled read), B = Wd columns.
    if (!isL1 && wv < 4) {
        const int colD = wv * 16 + n;
        short8 wd0, wd1;
#pragma unroll
        for (int j = 0; j < 8; ++j) {
            wd0[j] = f2bf(Wd[(q * 8 + j) * 64 + colD] * (-LG));
            wd1[j] = f2bf(Wd[(32 + q * 8 + j) * 64 + colD] * (-LG));
        }
        short8 hA0 = *(const short8*)&h2b[1][hro0];
        short8 hA1 = *(const short8*)&h2b[1][hro1];
        const float bdv = bd[colD] * (-LG);
        floatx4 dacc = { bdv, bdv, bdv, bdv };
        dacc = MFMA_BF16(hA0, wd0, dacc, 0, 0, 0);
        dacc = MFMA_BF16(hA1, wd1, dacc, 0, 0, 0);
        const float wo = Wo[colD];
#pragma unroll
        for (int r = 0; r < 4; ++r) {
            float p = rcp_(1.0f + ex2(dacc[r])) * wo;   // sigm (scale folded)
            p += __shfl_xor(p, 1, 64);
            p += __shfl_xor(p, 2, 64);
            p += __shfl_xor(p, 4, 64);
            p += __shfl_xor(p, 8, 64);                  // sum over 16 dense units
            if (n == 0) psum[wv][q * 4 + r] = p;
        }
    }
    __syncthreads();
    if (tid < 16) {
        float s = psum[0][tid] + psum[1][tid] + psum[2][tid] + psum[3][tid] + bo[0];
        out[b0 + tid] = sigm(s);
    }
}

extern "C" void kernel_launch(void* const* d_in, const int* in_sizes, int n_in,
                              void* d_out, int out_size, void* d_ws, size_t ws_size,
                              hipStream_t stream) {
    (void)in_sizes; (void)n_in; (void)d_ws; (void)ws_size; (void)out_size;
    const float* x  = (const float*)d_in[0];
    const float* W1 = (const float*)d_in[1];
    const float* U1 = (const float*)d_in[2];
    const float* b1 = (const float*)d_in[3];
    const float* W2 = (const float*)d_in[4];
    const float* U2 = (const float*)d_in[5];
    const float* b2 = (const float*)d_in[6];
    const float* Wd = (const float*)d_in[7];
    const float* bd = (const float*)d_in[8];
    const float* Wo = (const float*)d_in[9];
    const float* bo = (const float*)d_in[10];
    lstm2_tz<<<dim3(256), dim3(1024), 0, stream>>>(
        x, W1, U1, b1, W2, U2, b2, Wd, bd, Wo, bo, (float*)d_out);
}

// Round 6
// 326.186 us; speedup vs baseline: 1.1242x; 1.0131x over previous
//
#include <hip/hip_runtime.h>

// Fused 2-layer LSTM (H=64) + Dense(64,sigmoid) + Dense(1,sigmoid), MFMA bf16.
// Transposed-z formulation: z^T[gate-unit, batch] = Wt @ [x|h]^T.
// B=4096, T=256, F=32. One WG = 1024 threads = 16 waves handles BB=16 rows.
// Waves 0-7 (L1): layer 1 step u, 2 M-tiles each; waves 8-15 (L2): layer 2
// step u-1, 2 M-tiles each. One barrier per step; double-buffered h1/h2/x.
//
// ISSUE-BOUND (R5-confirmed): VALUBusy*dur == hand-counted issue cycles;
// instruction cuts give near-proportional speedups. R6 continues cutting:
//  - PACKED-F32 gate math: the two cells per lane (tt=0,1) are identical
//    dataflow -> all non-trans gate arithmetic on floatx2 so clang emits
//    VOP3P v_pk_{add,mul,fma}_f32 (gfx90a+). ~38 scalar -> ~19 packed.
//  - Wider rcp batching: ONE v_rcp for all 8 gate sigmoid denominators of
//    the cell pair (product-inversion; overflow needs sum|z|>88 ~ 30 sigma,
//    impossible here) + ONE v_rcp for the two tanh(c) denominators.
//    Trans: 14 -> 12 per wave-step (10 ex2 + 2 rcp).
// In-loop barrier stays raw "s_waitcnt lgkmcnt(0); s_barrier" (no vmcnt
// drain; x HBM prefetch stays in flight). u-loop unrolled x2, static parity.
// h layout: stride 64 shorts, XOR-swizzled per 16B chunk (chunk'=chunk^
// (batch&7)) -> conflict-free ds_read_b128. Lane (n,q) owns 2 consecutive
// units -> one b32 v_cvt_pk_bf16_f32 h-write per step. Activation scales
// folded into weights (i,f,o: -log2e; g: +2*log2e); cell state pre-scaled
// by 2*log2e; bias via MFMA C operand.
// MFMA 16x16x32 layouts (learn_hip-verified):
//   A[m=lane&15][k=(lane>>4)*8+j], B[k=(lane>>4)*8+j][n=lane&15],
//   C/D: col=lane&15, row=(lane>>4)*4+reg.

typedef __attribute__((ext_vector_type(8))) short short8;
typedef __attribute__((ext_vector_type(4))) float floatx4;
typedef __attribute__((ext_vector_type(2))) float floatx2;

__device__ __forceinline__ float ex2(float x){ return __builtin_amdgcn_exp2f(x); }
__device__ __forceinline__ float rcp_(float x){ return __builtin_amdgcn_rcpf(x); }
__device__ __forceinline__ float sigm(float x){ return rcp_(1.0f + ex2(-1.44269504f*x)); }
__device__ __forceinline__ unsigned bfbits(float f){       // RNE f32->bf16 (raw bits)
    unsigned u = __builtin_bit_cast(unsigned, f);
    u += 0x7FFFu + ((u >> 16) & 1u);
    return u >> 16;
}
__device__ __forceinline__ short f2bf(float f){ return (short)bfbits(f); }
// HW packed RNE f32->2xbf16 (bit-identical to bfbits for normals).
__device__ __forceinline__ unsigned cvtpk(float lo, float hi){
    unsigned r;
    asm("v_cvt_pk_bf16_f32 %0, %1, %2" : "=v"(r) : "v"(lo), "v"(hi));
    return r;
}
// Workgroup barrier WITHOUT vmcnt drain: LDS ordering via lgkmcnt(0) only.
__device__ __forceinline__ void wg_barrier_lds(){
    asm volatile("s_waitcnt lgkmcnt(0)\n\ts_barrier" ::: "memory");
}
__device__ __forceinline__ floatx2 pk2(float a){ return (floatx2){a, a}; }

// Gate math for the CELL PAIR (tt=0,1), packed f32x2 across cells.
// zA/zB pre-scaled (i,f,o: -LG; g: +2LG); c pre-scaled by 2*log2e.
// Trans: 10 ex2 + 2 rcp. Non-trans: ~19 packed + ~5 scalar ops.
__device__ __forceinline__ floatx2 gate_update_pair(const floatx4& zA, const floatx4& zB, floatx2& c){
    floatx2 ea = pk2(1.0f) + (floatx2){ex2(zA[0]), ex2(zB[0])};   // 1+e, gate i
    floatx2 eb = pk2(1.0f) + (floatx2){ex2(zA[1]), ex2(zB[1])};   // gate f
    floatx2 eg = pk2(1.0f) + (floatx2){ex2(zA[2]), ex2(zB[2])};   // gate g
    floatx2 eo = pk2(1.0f) + (floatx2){ex2(zA[3]), ex2(zB[3])};   // gate o
    floatx2 ab = ea * eb, gd = eg * eo;
    floatx2 abgd = ab * gd;                                       // per-cell P
    float r8 = rcp_(abgd.x * abgd.y);                             // 1/(P0*P1)
    floatx2 rc = (floatx2){ r8 * abgd.y, r8 * abgd.x };           // 1/P per cell
    floatx2 gdr = gd * rc, abr = ab * rc;                         // 1/ab, 1/gd
    floatx2 iv = eb * gdr, fv = ea * gdr;                         // sig(i), sig(f)
    floatx2 rg = eo * abr, ov = eg * abr;                         // sig(g'), sig(o)
    floatx2 gp = pk2(-5.77078016f) * rg + pk2(2.88539008f);       // 2LG*tanh(zg)
    c = fv * c + iv * gp;
    floatx2 dc = pk2(1.0f) + (floatx2){ex2(c.x), ex2(c.y)};
    float rr = rcp_(dc.x * dc.y);                                 // batched tanh rcp
    floatx2 rdc = (floatx2){ rr * dc.y, rr * dc.x };
    floatx2 th = pk2(-2.0f) * rdc + pk2(1.0f);                    // tanh(c/2LG)
    return ov * th;
}

#define MFMA_BF16 __builtin_amdgcn_mfma_f32_16x16x32_bf16

__global__ __launch_bounds__(1024, 1)
void lstm2_tz(const float* __restrict__ x,
              const float* __restrict__ W1, const float* __restrict__ U1, const float* __restrict__ b1,
              const float* __restrict__ W2, const float* __restrict__ U2, const float* __restrict__ b2,
              const float* __restrict__ Wd, const float* __restrict__ bd,
              const float* __restrict__ Wo, const float* __restrict__ bo,
              float* __restrict__ out)
{
    __shared__ __align__(16) short h1b[2][16 * 64];   // [buf][batch*64 + swz-unit]
    __shared__ __align__(16) short h2b[2][16 * 64];
    __shared__ __align__(16) short xsb[2][16 * 40];   // [buf][batch*40 + feat]
    __shared__ float psum[4][16];

    const int tid  = threadIdx.x;
    const int w    = tid >> 6;            // 0..15
    const bool isL1 = (w < 8);
    const int wv   = w & 7;               // 0..7 within group
    const int lane = tid & 63;
    const int n    = lane & 15;           // B-frag col = batch row; also A-frag m
    const int q    = lane >> 4;           // quad
    const int b0   = blockIdx.x * 16;

    const float LG = 1.44269504f;         // log2(e)

    // A-frag row mapping: within-tile row m -> (unit_local = m>>2, gate = m&3)
    const int ugl = n >> 2;
    const int gA  = n & 3;
    const float sA = (gA == 2) ? (2.0f * LG) : (-LG);

    // ---- per-lane LDS offsets (shorts), swizzle sw = n&7 on 16B chunks ----
    const int sw   = n & 7;
    const int hro0 = n * 64 + ((q ^ sw) << 3);          // h chunk q      (k 0..31)
    const int hro1 = n * 64 + (((4 + q) ^ sw) << 3);    // h chunk 4+q    (k 32..63)
    const int xro  = n * 40 + q * 8;
    // write: units wv*8+q*2+{0,1} -> chunk wv, in-chunk q*2 shorts (b32 store)
    const int hwo  = n * 64 + ((wv ^ sw) << 3) + q * 2;

    // ---- one-time: weight A-fragments + bias C vectors ----
    short8  Wa[8];
    floatx4 bC[2];
    if (isL1) {
#pragma unroll
        for (int tt = 0; tt < 2; ++tt) {
            const int un   = wv * 8 + ugl * 2 + tt;     // A-frag output unit
            const int ncol = gA * 64 + un;
#pragma unroll
            for (int j = 0; j < 8; ++j) {
                const int k = q * 8 + j;
                Wa[tt * 3 + 0][j] = f2bf(W1[k * 256 + ncol] * sA);
                Wa[tt * 3 + 1][j] = f2bf(U1[k * 256 + ncol] * sA);
                Wa[tt * 3 + 2][j] = f2bf(U1[(32 + k) * 256 + ncol] * sA);
            }
#pragma unroll
            for (int r = 0; r < 4; ++r)
                bC[tt][r] = b1[r * 64 + wv * 8 + q * 2 + tt] * ((r == 2) ? (2.0f * LG) : (-LG));
        }
    } else {
#pragma unroll
        for (int tt = 0; tt < 2; ++tt) {
            const int un   = wv * 8 + ugl * 2 + tt;
            const int ncol = gA * 64 + un;
#pragma unroll
            for (int j = 0; j < 8; ++j) {
                const int k = q * 8 + j;
                Wa[tt * 4 + 0][j] = f2bf(W2[k * 256 + ncol] * sA);
                Wa[tt * 4 + 1][j] = f2bf(W2[(32 + k) * 256 + ncol] * sA);
                Wa[tt * 4 + 2][j] = f2bf(U2[k * 256 + ncol] * sA);
                Wa[tt * 4 + 3][j] = f2bf(U2[(32 + k) * 256 + ncol] * sA);
            }
#pragma unroll
            for (int r = 0; r < 4; ++r)
                bC[tt][r] = b2[r * 64 + wv * 8 + q * 2 + tt] * ((r == 2) ? (2.0f * LG) : (-LG));
        }
    }

    // ---- zero h double-buffers ----
    {
        unsigned* p1 = (unsigned*)&h1b[0][0];
        unsigned* p2 = (unsigned*)&h2b[0][0];
        for (int i = tid; i < 1024; i += 1024) { p1[i] = 0u; p2[i] = 0u; }
    }

    // ---- x staging (tid<256 = L1 waves 0-3): 2 fp32 of row (tid>>4)/step ----
    const int xr = tid >> 4;
    const int xc = (tid & 15) * 2;
    const float* xrow = x + (size_t)(b0 + xr) * 8192 + xc;   // T*F = 8192
    floatx2 xv0;
    if (tid < 256) {
        floatx2 v = *(const floatx2*)xrow;                    // x[0]
        *(unsigned*)&xsb[0][xr * 40 + xc] = cvtpk(v.x, v.y);
        xv0 = *(const floatx2*)(xrow + 32);                   // x[1]
    }
    __syncthreads();

    floatx2 c = {0.0f, 0.0f};             // cell-pair state, pre-scaled by 2*log2e

    // One LSTM step at compile-time parity PAR (reads h[1-PAR], writes h[PAR]).
#define LSTM_STEP(U, PAR)                                                     \
    {                                                                         \
        const int u_ = (U);                                                   \
        if (isL1) {                                                           \
            if (u_ < 256) {                                                   \
                const short* hR = &h1b[1 - (PAR)][0];                         \
                short8 bx  = *(const short8*)&xsb[(PAR)][xro];                \
                short8 bh0 = *(const short8*)&hR[hro0];                       \
                short8 bh1 = *(const short8*)&hR[hro1];                       \
                if (tid < 256 && u_ < 255) {                                  \
                    *(unsigned*)&xsb[1 - (PAR)][xr * 40 + xc] = cvtpk(xv0.x, xv0.y); \
                    if (u_ < 254) xv0 = *(const floatx2*)(xrow + (size_t)(u_ + 2) * 32); \
                }                                                             \
                floatx4 zA = bC[0];                                           \
                zA = MFMA_BF16(Wa[0], bx,  zA, 0, 0, 0);                      \
                zA = MFMA_BF16(Wa[1], bh0, zA, 0, 0, 0);                      \
                zA = MFMA_BF16(Wa[2], bh1, zA, 0, 0, 0);                      \
                floatx4 zB = bC[1];                                           \
                zB = MFMA_BF16(Wa[3], bx,  zB, 0, 0, 0);                      \
                zB = MFMA_BF16(Wa[4], bh0, zB, 0, 0, 0);                      \
                zB = MFMA_BF16(Wa[5], bh1, zB, 0, 0, 0);                      \
                floatx2 hv = gate_update_pair(zA, zB, c);                     \
                *(unsigned*)&h1b[(PAR)][hwo] = cvtpk(hv.x, hv.y);             \
            }                                                                 \
        } else {                                                              \
            if (u_ >= 1 && u_ <= 256) {                                       \
                const short* hR = &h1b[1 - (PAR)][0];                         \
                const short* gR = &h2b[(PAR)][0];                             \
                short8 bh0 = *(const short8*)&hR[hro0];                       \
                short8 bh1 = *(const short8*)&hR[hro1];                       \
                short8 bg0 = *(const short8*)&gR[hro0];                       \
                short8 bg1 = *(const short8*)&gR[hro1];                       \
                floatx4 zA = bC[0];                                           \
                zA = MFMA_BF16(Wa[0], bh0, zA, 0, 0, 0);                      \
                zA = MFMA_BF16(Wa[1], bh1, zA, 0, 0, 0);                      \
                zA = MFMA_BF16(Wa[2], bg0, zA, 0, 0, 0);                      \
                zA = MFMA_BF16(Wa[3], bg1, zA, 0, 0, 0);                      \
                floatx4 zB = bC[1];                                           \
                zB = MFMA_BF16(Wa[4], bh0, zB, 0, 0, 0);                      \
                zB = MFMA_BF16(Wa[5], bh1, zB, 0, 0, 0);                      \
                zB = MFMA_BF16(Wa[6], bg0, zB, 0, 0, 0);                      \
                zB = MFMA_BF16(Wa[7], bg1, zB, 0, 0, 0);                      \
                floatx2 hv = gate_update_pair(zA, zB, c);                     \
                *(unsigned*)&h2b[1 - (PAR)][hwo] = cvtpk(hv.x, hv.y);         \
            }                                                                 \
        }                                                                     \
        wg_barrier_lds();                                                     \
    }

    // u = 0..257 (u=257 is a barrier-only pad step), static parity via x2 unroll.
    for (int uu = 0; uu < 258; uu += 2) {
        LSTM_STEP(uu,     0)
        LSTM_STEP(uu + 1, 1)
    }
#undef LSTM_STEP

    // ---- epilogue (waves 8-11): h_last = h2[255] in h2b[1] ----
    // Dense(64,sigmoid): A = h2 rows (swizzled read), B = Wd columns.
    if (!isL1 && wv < 4) {
        const int colD = wv * 16 + n;
        short8 wd0, wd1;
#pragma unroll
        for (int j = 0; j < 8; ++j) {
            wd0[j] = f2bf(Wd[(q * 8 + j) * 64 + colD] * (-LG));
            wd1[j] = f2bf(Wd[(32 + q * 8 + j) * 64 + colD] * (-LG));
        }
        short8 hA0 = *(const short8*)&h2b[1][hro0];
        short8 hA1 = *(const short8*)&h2b[1][hro1];
        const float bdv = bd[colD] * (-LG);
        floatx4 dacc = { bdv, bdv, bdv, bdv };
        dacc = MFMA_BF16(hA0, wd0, dacc, 0, 0, 0);
        dacc = MFMA_BF16(hA1, wd1, dacc, 0, 0, 0);
        const float wo = Wo[colD];
#pragma unroll
        for (int r = 0; r < 4; ++r) {
            float p = rcp_(1.0f + ex2(dacc[r])) * wo;   // sigm (scale folded)
            p += __shfl_xor(p, 1, 64);
            p += __shfl_xor(p, 2, 64);
            p += __shfl_xor(p, 4, 64);
            p += __shfl_xor(p, 8, 64);                  // sum over 16 dense units
            if (n == 0) psum[wv][q * 4 + r] = p;
        }
    }
    __syncthreads();
    if (tid < 16) {
        float s = psum[0][tid] + psum[1][tid] + psum[2][tid] + psum[3][tid] + bo[0];
        out[b0 + tid] = sigm(s);
    }
}

extern "C" void kernel_launch(void* const* d_in, const int* in_sizes, int n_in,
                              void* d_out, int out_size, void* d_ws, size_t ws_size,
                              hipStream_t stream) {
    (void)in_sizes; (void)n_in; (void)d_ws; (void)ws_size; (void)out_size;
    const float* x  = (const float*)d_in[0];
    const float* W1 = (const float*)d_in[1];
    const float* U1 = (const float*)d_in[2];
    const float* b1 = (const float*)d_in[3];
    const float* W2 = (const float*)d_in[4];
    const float* U2 = (const float*)d_in[5];
    const float* b2 = (const float*)d_in[6];
    const float* Wd = (const float*)d_in[7];
    const float* bd = (const float*)d_in[8];
    const float* Wo = (const float*)d_in[9];
    const float* bo = (const float*)d_in[10];
    lstm2_tz<<<dim3(256), dim3(1024), 0, stream>>>(
        x, W1, U1, b1, W2, U2, b2, Wd, bd, Wo, bo, (float*)d_out);
}